// Round 7
// baseline (306.270 us; speedup 1.0000x reference)
//
#include <hip/hip_runtime.h>
#include <stdint.h>

#define NS 150
#define D_IN 1024
#define D_H 512
#define D_OUT 256

typedef __bf16 bf16x8 __attribute__((ext_vector_type(8)));
typedef float f32x4 __attribute__((ext_vector_type(4)));

// ---- workspace layout (float offsets) ----
#define OFF_XF    0u          // x fragments, 32768 bf16 (MFMA B-operand order)
#define OFF_MS1T  16384u      // float2[512*1024] (mu,std) at [h][i]
#define OFF_MS2T  1064960u    // float2[256*512]  (mu,std) at [o][h]
#define OFF_B1S   1327104u    // 150*512 = 76800
#define OFF_B2S   1403904u    // 150*256 = 38400
#define OFF_HB    1442304u    // h bf16 FRAGMENT layout [n][s:16][bh:2][qp:4][b16:16][j:8]
                              // element (n, b, h): s=h>>5, qp=(h>>3)&3, j=h&7, bh=b>>4, b16=b&15

// sqrt(2)-folded ErfInv coefficients
#define SQ2 1.41421354f

// Main-branch Horner re-based into z = log2(t) domain:
//   w = -ln2*z ; ww = w-2.5 = -ln2*(z + 2.5/ln2) ; coeffs folded by (-ln2)^k.
#define DSQ2 1.4142135623730951
#define DA  (-0.6931471805599453)
#define ZC3 ((float)(DSQ2 * -4.39150654e-06 * DA*DA*DA*DA*DA))
#define ZC4 ((float)(DSQ2 * 0.00021858087   * DA*DA*DA*DA))
#define ZC5 ((float)(DSQ2 * -0.00125372503  * DA*DA*DA))
#define ZC6 ((float)(DSQ2 * -0.00417768164  * DA*DA))
#define ZC7 ((float)(DSQ2 * 0.246640727     * DA))
#define ZC8 ((float)(DSQ2 * 1.50140941))
#define ZSHIFT 3.6067376022224085f   /* 2.5/ln2 */
#define ZCUT  -7.213475204444817f    /* -(5/ln2): main branch iff z > ZCUT */

// Tail coeffs (exact, sqrt(2)-folded)
#define TT0 (SQ2 * -0.000200214257f)
#define TT1 (SQ2 * 0.000100950558f)
#define TT2 (SQ2 * 0.00134934322f)
#define TT3 (SQ2 * -0.00367342844f)
#define TT4 (SQ2 * 0.00573950773f)
#define TT5 (SQ2 * -0.0076224613f)
#define TT6 (SQ2 * 0.00943887047f)
#define TT7 (SQ2 * 1.00167406f)
#define TT8 (SQ2 * 2.83297682f)

// ---------- threefry-2x32 (JAX-exact, 20 rounds) ----------
#define ROTL32(x, r) __builtin_rotateleft32((x), (r))

__host__ __device__ __forceinline__ void threefry2x32(uint32_t k0, uint32_t k1,
                                                      uint32_t x0, uint32_t x1,
                                                      uint32_t& o0, uint32_t& o1) {
  uint32_t k2 = k0 ^ k1 ^ 0x1BD11BDAu;
  x0 += k0; x1 += k1;
#define TFR(r) { x0 += x1; x1 = ROTL32(x1, r); x1 ^= x0; }
  TFR(13) TFR(15) TFR(26) TFR(6)
  x0 += k1; x1 += k2 + 1u;
  TFR(17) TFR(29) TFR(16) TFR(24)
  x0 += k2; x1 += k0 + 2u;
  TFR(13) TFR(15) TFR(26) TFR(6)
  x0 += k0; x1 += k1 + 3u;
  TFR(17) TFR(29) TFR(16) TFR(24)
  x0 += k1; x1 += k2 + 4u;
  TFR(13) TFR(15) TFR(26) TFR(6)
  x0 += k2; x1 += k0 + 5u;
#undef TFR
  o0 = x0; o1 = x1;
}

// scalar path (bias staging) — exact 9-term
__device__ __forceinline__ float tf_normal(uint32_t k0, uint32_t k1, uint32_t idx) {
  uint32_t o0, o1;
  threefry2x32(k0, k1, 0u, idx, o0, o1);
  uint32_t bits = o0 ^ o1;
  uint32_t fb = (bits >> 9) | 0x3F800000u;
  float m = __uint_as_float(fb);
  const float lo = -0.99999994f;
  float u = fmaxf(fmaf(m, 2.0f, -3.0f), lo);
  float t = fmaf(u, -u, 1.0f);
  float w = -0.69314718056f * __builtin_amdgcn_logf(t);
  float p;
  if (w < 5.0f) {
    float ww = w - 2.5f;
    p = SQ2 * 2.81022636e-08f;
    p = fmaf(p, ww, SQ2 * 3.43273939e-07f);
    p = fmaf(p, ww, SQ2 * -3.5233877e-06f);
    p = fmaf(p, ww, SQ2 * -4.39150654e-06f);
    p = fmaf(p, ww, SQ2 * 0.00021858087f);
    p = fmaf(p, ww, SQ2 * -0.00125372503f);
    p = fmaf(p, ww, SQ2 * -0.00417768164f);
    p = fmaf(p, ww, SQ2 * 0.246640727f);
    p = fmaf(p, ww, SQ2 * 1.50140941f);
  } else {
    float ww = __builtin_amdgcn_sqrtf(w) - 3.0f;
    p = TT0;
    p = fmaf(p, ww, TT1); p = fmaf(p, ww, TT2); p = fmaf(p, ww, TT3);
    p = fmaf(p, ww, TT4); p = fmaf(p, ww, TT5); p = fmaf(p, ww, TT6);
    p = fmaf(p, ww, TT7); p = fmaf(p, ww, TT8);
  }
  return p * u;
}

// ---------- 8-chain threefry: INLINE ASM with injection folding (R2-proven) ----------
#define TF_ADD8 \
  "v_add_u32 %[a0], %[a0], %[b0]\n\t" "v_add_u32 %[a1], %[a1], %[b1]\n\t" \
  "v_add_u32 %[a2], %[a2], %[b2]\n\t" "v_add_u32 %[a3], %[a3], %[b3]\n\t" \
  "v_add_u32 %[a4], %[a4], %[b4]\n\t" "v_add_u32 %[a5], %[a5], %[b5]\n\t" \
  "v_add_u32 %[a6], %[a6], %[b6]\n\t" "v_add_u32 %[a7], %[a7], %[b7]\n\t"
#define TF_ROT8(sh) \
  "v_alignbit_b32 %[b0], %[b0], %[b0], " sh "\n\t" \
  "v_alignbit_b32 %[b1], %[b1], %[b1], " sh "\n\t" \
  "v_alignbit_b32 %[b2], %[b2], %[b2], " sh "\n\t" \
  "v_alignbit_b32 %[b3], %[b3], %[b3], " sh "\n\t" \
  "v_alignbit_b32 %[b4], %[b4], %[b4], " sh "\n\t" \
  "v_alignbit_b32 %[b5], %[b5], %[b5], " sh "\n\t" \
  "v_alignbit_b32 %[b6], %[b6], %[b6], " sh "\n\t" \
  "v_alignbit_b32 %[b7], %[b7], %[b7], " sh "\n\t"
#define TF_XOR8 \
  "v_xor_b32 %[b0], %[b0], %[a0]\n\t" "v_xor_b32 %[b1], %[b1], %[a1]\n\t" \
  "v_xor_b32 %[b2], %[b2], %[a2]\n\t" "v_xor_b32 %[b3], %[b3], %[a3]\n\t" \
  "v_xor_b32 %[b4], %[b4], %[a4]\n\t" "v_xor_b32 %[b5], %[b5], %[a5]\n\t" \
  "v_xor_b32 %[b6], %[b6], %[a6]\n\t" "v_xor_b32 %[b7], %[b7], %[a7]\n\t"
#define TF_ROUND(sh) TF_ADD8 TF_ROT8(sh) TF_XOR8
// round 1: a = k0 + b (SGPR src0)
#define TF_R1(sh) \
  "v_add_u32 %[a0], %[k0], %[b0]\n\t" "v_add_u32 %[a1], %[k0], %[b1]\n\t" \
  "v_add_u32 %[a2], %[k0], %[b2]\n\t" "v_add_u32 %[a3], %[k0], %[b3]\n\t" \
  "v_add_u32 %[a4], %[k0], %[b4]\n\t" "v_add_u32 %[a5], %[k0], %[b5]\n\t" \
  "v_add_u32 %[a6], %[k0], %[b6]\n\t" "v_add_u32 %[a7], %[k0], %[b7]\n\t" \
  TF_ROT8(sh) TF_XOR8
#define TF_BADD8(KB) \
  "v_add_u32 %[b0], " KB ", %[b0]\n\t" "v_add_u32 %[b1], " KB ", %[b1]\n\t" \
  "v_add_u32 %[b2], " KB ", %[b2]\n\t" "v_add_u32 %[b3], " KB ", %[b3]\n\t" \
  "v_add_u32 %[b4], " KB ", %[b4]\n\t" "v_add_u32 %[b5], " KB ", %[b5]\n\t" \
  "v_add_u32 %[b6], " KB ", %[b6]\n\t" "v_add_u32 %[b7], " KB ", %[b7]\n\t"
#define TF_AADD8(KA) \
  "v_add_u32 %[a0], " KA ", %[a0]\n\t" "v_add_u32 %[a1], " KA ", %[a1]\n\t" \
  "v_add_u32 %[a2], " KA ", %[a2]\n\t" "v_add_u32 %[a3], " KA ", %[a3]\n\t" \
  "v_add_u32 %[a4], " KA ", %[a4]\n\t" "v_add_u32 %[a5], " KA ", %[a5]\n\t" \
  "v_add_u32 %[a6], " KA ", %[a6]\n\t" "v_add_u32 %[a7], " KA ", %[a7]\n\t"
#define TF_A3F(KA) \
  "v_add3_u32 %[a0], %[a0], %[b0], " KA "\n\t" \
  "v_add3_u32 %[a1], %[a1], %[b1], " KA "\n\t" \
  "v_add3_u32 %[a2], %[a2], %[b2], " KA "\n\t" \
  "v_add3_u32 %[a3], %[a3], %[b3], " KA "\n\t" \
  "v_add3_u32 %[a4], %[a4], %[b4], " KA "\n\t" \
  "v_add3_u32 %[a5], %[a5], %[b5], " KA "\n\t" \
  "v_add3_u32 %[a6], %[a6], %[b6], " KA "\n\t" \
  "v_add3_u32 %[a7], %[a7], %[b7], " KA "\n\t"
// injection (b += KB) + next round (a = a + b + KA; rot; xor), folded
#define TF_RFOLD(KB, KA, sh) TF_BADD8(KB) TF_A3F(KA) TF_ROT8(sh) TF_XOR8

__device__ __forceinline__ void tf8_bits(uint32_t k0, uint32_t k1, uint32_t k2,
                                         uint32_t idx0, uint32_t* bits) {
  uint32_t k2p1 = k2 + 1u, k0p2 = k0 + 2u, k1p3 = k1 + 3u;
  uint32_t k2p4 = k2 + 4u, k0p5 = k0 + 5u;
  uint32_t t0 = idx0 + k1;
  uint32_t a0, a1, a2, a3, a4, a5, a6, a7;
  uint32_t b0 = t0, b1 = t0 + 1u, b2 = t0 + 2u, b3 = t0 + 3u;
  uint32_t b4 = t0 + 4u, b5 = t0 + 5u, b6 = t0 + 6u, b7 = t0 + 7u;
  asm(TF_R1("19") TF_ROUND("17") TF_ROUND("6") TF_ROUND("26")
      TF_RFOLD("%[k2p1]", "%[k1]", "15")
      TF_ROUND("3") TF_ROUND("16") TF_ROUND("8")
      TF_RFOLD("%[k0p2]", "%[k2]", "19")
      TF_ROUND("17") TF_ROUND("6") TF_ROUND("26")
      TF_RFOLD("%[k1p3]", "%[k0]", "15")
      TF_ROUND("3") TF_ROUND("16") TF_ROUND("8")
      TF_RFOLD("%[k2p4]", "%[k1]", "19")
      TF_ROUND("17") TF_ROUND("6") TF_ROUND("26")
      TF_AADD8("%[k2]") TF_BADD8("%[k0p5]")
      : [a0]"=&v"(a0), [a1]"=&v"(a1), [a2]"=&v"(a2), [a3]"=&v"(a3),
        [a4]"=&v"(a4), [a5]"=&v"(a5), [a6]"=&v"(a6), [a7]"=&v"(a7),
        [b0]"+v"(b0), [b1]"+v"(b1), [b2]"+v"(b2), [b3]"+v"(b3),
        [b4]"+v"(b4), [b5]"+v"(b5), [b6]"+v"(b6), [b7]"+v"(b7)
      : [k0]"s"(k0), [k1]"s"(k1), [k2]"s"(k2), [k2p1]"s"(k2p1),
        [k0p2]"s"(k0p2), [k1p3]"s"(k1p3), [k2p4]"s"(k2p4), [k0p5]"s"(k0p5));
  bits[0] = a0 ^ b0; bits[1] = a1 ^ b1; bits[2] = a2 ^ b2; bits[3] = a3 ^ b3;
  bits[4] = a4 ^ b4; bits[5] = a5 ^ b5; bits[6] = a6 ^ b6; bits[7] = a7 ^ b7;
}

// ---------- transform: scalar C code (R0/R2/R3-proven) ----------
__device__ __forceinline__ float bits_normal(uint32_t bits) {
  uint32_t fb = (bits >> 9) | 0x3F800000u;
  float m = __uint_as_float(fb);
  const float lo = -0.99999994f;
  float u = fmaxf(fmaf(m, 2.0f, -3.0f), lo);
  float t = fmaf(u, -u, 1.0f);
  float z = __builtin_amdgcn_logf(t);          // log2(t) <= 0
  float p;
  if (z > ZCUT) {                              // w < 5 (common)
    float zz = z + ZSHIFT;
    p = ZC3;
    p = fmaf(p, zz, ZC4); p = fmaf(p, zz, ZC5); p = fmaf(p, zz, ZC6);
    p = fmaf(p, zz, ZC7); p = fmaf(p, zz, ZC8);
  } else {                                     // rare tail: exact
    float w = -0.69314718056f * z;
    float ww = __builtin_amdgcn_sqrtf(w) - 3.0f;
    p = TT0;
    p = fmaf(p, ww, TT1); p = fmaf(p, ww, TT2); p = fmaf(p, ww, TT3);
    p = fmaf(p, ww, TT4); p = fmaf(p, ww, TT5); p = fmaf(p, ww, TT6);
    p = fmaf(p, ww, TT7); p = fmaf(p, ww, TT8);
  }
  return p * u;
}

// ---------- prep: full staging (R2-proven) ----------
__global__ __launch_bounds__(256) void prep_kernel(
    const float* __restrict__ x,
    const float* __restrict__ muW1, const float* __restrict__ vW1,
    const float* __restrict__ muW2, const float* __restrict__ vW2,
    const float* __restrict__ mub1, const float* __restrict__ vb1,
    const float* __restrict__ mub2, const float* __restrict__ vb2,
    float* __restrict__ ws,
    uint32_t kb1_0, uint32_t kb1_1, uint32_t kb2_0, uint32_t kb2_1) {
  int bb = blockIdx.x;
  int tid = threadIdx.x;
  if (bb < 2048) {
    int t = bb * 256 + tid;                       // MS1T [h][i] flat
    ((float2*)(ws + OFF_MS1T))[t] = make_float2(muW1[t], expf(vW1[t]));
  } else if (bb < 2560) {
    int t = (bb - 2048) * 256 + tid;              // MS2T [o][h] flat
    ((float2*)(ws + OFF_MS2T))[t] = make_float2(muW2[t], expf(vW2[t]));
  } else if (bb < 2688) {
    int t = (bb - 2560) * 256 + tid;              // x fragments, B-operand order
    int j = t & 7, lane = (t >> 3) & 63, fidx = t >> 9;
    int s = fidx >> 1, f = fidx & 1;
    int b = f * 16 + (lane & 15);
    int k = s * 32 + ((lane >> 4) << 3) + j;
    ((__bf16*)(ws + OFF_XF))[t] = (__bf16)x[b * D_IN + k];
  } else if (bb < 2988) {
    int t = (bb - 2688) * 256 + tid;              // b1s
    int h = t & 511;
    float eps = tf_normal(kb1_0, kb1_1, (uint32_t)t);
    ws[OFF_B1S + t] = fmaf(eps, expf(vb1[h]), mub1[h]);
  } else {
    int t = (bb - 2988) * 256 + tid;              // b2s
    int o = t & 255;
    float eps = tf_normal(kb2_0, kb2_1, (uint32_t)t);
    ws[OFF_B2S + t] = fmaf(eps, expf(vb2[o]), mub2[o]);
  }
}

// ---------- layer 1: K-split 2, 128-thread blocks (R3-proven) + 1-deep
// load prefetch: next iteration's ms/xf loads issue before this iteration's
// ~600-instr tf8+transform block, hiding L2/L3 latency. ----------
__global__ __launch_bounds__(128) void l1_kernel(
    const float* __restrict__ ws, uint32_t k0, uint32_t k1) {
  const float2* __restrict__ ms1 = (const float2*)(ws + OFF_MS1T);
  const bf16x8* __restrict__ xf = (const bf16x8*)(ws + OFF_XF);
  const float* __restrict__ b1s = ws + OFF_B1S;
  __bf16* __restrict__ hB = (__bf16*)(ws + OFF_HB);
  uint32_t k2 = k0 ^ k1 ^ 0x1BD11BDAu;

  __shared__ f32x4 lred[2][64];   // 2048 B

  int lane = threadIdx.x & 63;
  int khalf = threadIdx.x >> 6;
  int tile = blockIdx.x;                 // 0..4799
  int n = tile >> 5;
  int ht = tile & 31;
  int mrow = lane & 15, quad = lane >> 4;
  int h = ht * 16 + mrow;
  uint32_t base = ((uint32_t)(n * 512 + h)) << 10;
  const float2* __restrict__ msrow = ms1 + (size_t)h * D_IN;

  f32x4 acc0 = {0.f, 0.f, 0.f, 0.f}, acc1 = {0.f, 0.f, 0.f, 0.f};

  int s0 = khalf * 16, send = s0 + 16;
  // prologue loads for s = s0
  const f32x4* msq = (const f32x4*)(msrow + s0 * 32 + quad * 8);
  f32x4 q0 = msq[0], q1 = msq[1], q2 = msq[2], q3 = msq[3];
  bf16x8 b0 = xf[(s0 * 2 + 0) * 64 + lane];
  bf16x8 b1 = xf[(s0 * 2 + 1) * 64 + lane];

  for (int s = s0; s < send; ++s) {
    // prefetch s+1 (uniform clamp keeps it in-bounds; last iter reloads s)
    int sp = (s + 1 < send) ? s + 1 : s;
    const f32x4* msqn = (const f32x4*)(msrow + sp * 32 + quad * 8);
    f32x4 nq0 = msqn[0], nq1 = msqn[1], nq2 = msqn[2], nq3 = msqn[3];
    bf16x8 nb0 = xf[(sp * 2 + 0) * 64 + lane];
    bf16x8 nb1 = xf[(sp * 2 + 1) * 64 + lane];

    int kq = s * 32 + quad * 8;
    uint32_t bits[8];
    tf8_bits(k0, k1, k2, base + (uint32_t)kq, bits);
    float mu[8], sd[8];
    mu[0]=q0[0]; sd[0]=q0[1]; mu[1]=q0[2]; sd[1]=q0[3];
    mu[2]=q1[0]; sd[2]=q1[1]; mu[3]=q1[2]; sd[3]=q1[3];
    mu[4]=q2[0]; sd[4]=q2[1]; mu[5]=q2[2]; sd[5]=q2[3];
    mu[6]=q3[0]; sd[6]=q3[1]; mu[7]=q3[2]; sd[7]=q3[3];
    bf16x8 a;
#pragma unroll
    for (int j = 0; j < 8; ++j) {
      float eps = bits_normal(bits[j]);
      a[j] = (__bf16)fmaf(eps, sd[j], mu[j]);
    }
    acc0 = __builtin_amdgcn_mfma_f32_16x16x32_bf16(a, b0, acc0, 0, 0, 0);
    acc1 = __builtin_amdgcn_mfma_f32_16x16x32_bf16(a, b1, acc1, 0, 0, 0);

    q0 = nq0; q1 = nq1; q2 = nq2; q3 = nq3;
    b0 = nb0; b1 = nb1;
  }

  if (khalf) {
    lred[0][lane] = acc0;
    lred[1][lane] = acc1;
  }
  __syncthreads();
  if (!khalf) {
    f32x4 r0 = lred[0][lane], r1 = lred[1][lane];
    acc0 += r0; acc1 += r1;
    int hq = ht * 16 + quad * 4;
    float4 bias = *(const float4*)(b1s + n * 512 + hq);
    float bv[4] = {bias.x, bias.y, bias.z, bias.w};
    union { __bf16 v[4]; uint2 u; } p0, p1;
#pragma unroll
    for (int r = 0; r < 4; ++r) {
      p0.v[r] = (__bf16)fmaxf(acc0[r] + bv[r], 0.0f);
      p1.v[r] = (__bf16)fmaxf(acc1[r] + bv[r], 0.0f);
    }
    // Fragment-layout store: [n][s:16][bh:2][qp:4][b16:16][j:8]  (R3-proven)
    size_t o0 = ((((size_t)(n * 16 + (ht >> 1)) * 2 + 0) * 4 +
                  ((ht & 1) * 2 + (quad >> 1))) * 16 + mrow) * 8 + (quad & 1) * 4;
    *(uint2*)(hB + o0) = p0.u;
    *(uint2*)(hB + o0 + 512) = p1.u;   // bh=1 stride = 4*16*8 = 512 bf16
  }
}

// ---------- layer 2: K-split 2, 256-thread blocks, 2 tiles/block (R6-proven
// best residual) + coalesced fragment hB loads + 1-deep prefetch ----------
__global__ __launch_bounds__(256) void l2_kernel(
    const float* __restrict__ ws, float* __restrict__ y,
    uint32_t k0, uint32_t k1) {
  const float2* __restrict__ ms2 = (const float2*)(ws + OFF_MS2T);
  const bf16x8* __restrict__ hB8 = (const bf16x8*)(ws + OFF_HB);
  const float* __restrict__ b2s = ws + OFF_B2S;
  uint32_t k2 = k0 ^ k1 ^ 0x1BD11BDAu;

  __shared__ f32x4 lred[2][2][64];   // 4096 B

  int lane = threadIdx.x & 63;
  int wib = threadIdx.x >> 6;
  int pairIdx = wib >> 1, khalf = wib & 1;
  int tile = blockIdx.x * 2 + pairIdx;   // 0..2399
  int n = tile >> 4;
  int ot = tile & 15;
  int mrow = lane & 15, quad = lane >> 4;
  int o = ot * 16 + mrow;
  uint32_t base = (uint32_t)(n * 256 + o) << 9;
  const float2* __restrict__ msrow = ms2 + (size_t)o * D_H;

  f32x4 acc0 = {0.f, 0.f, 0.f, 0.f}, acc1 = {0.f, 0.f, 0.f, 0.f};

  int s0 = khalf * 8, send = s0 + 8;
  const f32x4* msq = (const f32x4*)(msrow + s0 * 32 + quad * 8);
  f32x4 q0 = msq[0], q1 = msq[1], q2 = msq[2], q3 = msq[3];
  const bf16x8* hf = hB8 + (size_t)((n * 16 + s0) * 2) * 64;
  bf16x8 b0 = hf[lane];
  bf16x8 b1 = hf[64 + lane];

  for (int s = s0; s < send; ++s) {
    int sp = (s + 1 < send) ? s + 1 : s;
    const f32x4* msqn = (const f32x4*)(msrow + sp * 32 + quad * 8);
    f32x4 nq0 = msqn[0], nq1 = msqn[1], nq2 = msqn[2], nq3 = msqn[3];
    const bf16x8* hfn = hB8 + (size_t)((n * 16 + sp) * 2) * 64;
    bf16x8 nb0 = hfn[lane];
    bf16x8 nb1 = hfn[64 + lane];

    int kq = s * 32 + quad * 8;
    uint32_t bits[8];
    tf8_bits(k0, k1, k2, base + (uint32_t)kq, bits);
    float mu[8], sd[8];
    mu[0]=q0[0]; sd[0]=q0[1]; mu[1]=q0[2]; sd[1]=q0[3];
    mu[2]=q1[0]; sd[2]=q1[1]; mu[3]=q1[2]; sd[3]=q1[3];
    mu[4]=q2[0]; sd[4]=q2[1]; mu[5]=q2[2]; sd[5]=q2[3];
    mu[6]=q3[0]; sd[6]=q3[1]; mu[7]=q3[2]; sd[7]=q3[3];
    bf16x8 a;
#pragma unroll
    for (int j = 0; j < 8; ++j) {
      float eps = bits_normal(bits[j]);
      a[j] = (__bf16)fmaf(eps, sd[j], mu[j]);
    }
    acc0 = __builtin_amdgcn_mfma_f32_16x16x32_bf16(a, b0, acc0, 0, 0, 0);
    acc1 = __builtin_amdgcn_mfma_f32_16x16x32_bf16(a, b1, acc1, 0, 0, 0);

    q0 = nq0; q1 = nq1; q2 = nq2; q3 = nq3;
    b0 = nb0; b1 = nb1;
  }

  if (khalf) {
    lred[pairIdx][0][lane] = acc0;
    lred[pairIdx][1][lane] = acc1;
  }
  __syncthreads();
  if (!khalf) {
    f32x4 r0 = lred[pairIdx][0][lane], r1 = lred[pairIdx][1][lane];
    acc0 += r0; acc1 += r1;
    int oq = ot * 16 + quad * 4;
    float4 bias = *(const float4*)(b2s + n * 256 + oq);
    float4 o0, o1;
    o0.x = acc0[0] + bias.x; o0.y = acc0[1] + bias.y;
    o0.z = acc0[2] + bias.z; o0.w = acc0[3] + bias.w;
    o1.x = acc1[0] + bias.x; o1.y = acc1[1] + bias.y;
    o1.z = acc1[2] + bias.z; o1.w = acc1[3] + bias.w;
    *(float4*)(y + (size_t)(n * 32 + mrow) * 256 + oq) = o0;
    *(float4*)(y + (size_t)(n * 32 + 16 + mrow) * 256 + oq) = o1;
  }
}

extern "C" void kernel_launch(void* const* d_in, const int* in_sizes, int n_in,
                              void* d_out, int out_size, void* d_ws, size_t ws_size,
                              hipStream_t stream) {
  const float* x = (const float*)d_in[0];
  const float* muW1 = (const float*)d_in[1];
  const float* mub1 = (const float*)d_in[2];
  const float* muW2 = (const float*)d_in[3];
  const float* mub2 = (const float*)d_in[4];
  const float* vW1 = (const float*)d_in[5];
  const float* vb1 = (const float*)d_in[6];
  const float* vW2 = (const float*)d_in[7];
  const float* vb2 = (const float*)d_in[8];
  float* y = (float*)d_out;
  float* ws = (float*)d_ws;

  uint32_t nk[4][2];
  for (uint32_t j = 0; j < 4; ++j) {
    threefry2x32(0u, 42u, 0u, j, nk[j][0], nk[j][1]);
  }
  // eW1=nk[0], eb1=nk[1], eW2=nk[2], eb2=nk[3]

  prep_kernel<<<3138, 256, 0, stream>>>(
      x, muW1, vW1, muW2, vW2, mub1, vb1, mub2, vb2, ws,
      nk[1][0], nk[1][1], nk[3][0], nk[3][1]);

  // l1: 4800 tiles, one per 128-thread block (2 k-half waves)
  l1_kernel<<<4800, 128, 0, stream>>>(ws, nk[0][0], nk[0][1]);

  // l2: 2400 tiles x 2 k-halves = 4800 waves -> 1200 blocks x 256
  l2_kernel<<<1200, 256, 0, stream>>>(ws, y, nk[2][0], nk[2][1]);
}

// Round 8
// 292.506 us; speedup vs baseline: 1.0471x; 1.0471x over previous
//
#include <hip/hip_runtime.h>
#include <stdint.h>

#define NS 150
#define D_IN 1024
#define D_H 512
#define D_OUT 256

typedef __bf16 bf16x8 __attribute__((ext_vector_type(8)));
typedef float f32x4 __attribute__((ext_vector_type(4)));

// ---- workspace layout (float offsets) ----
#define OFF_XF    0u          // x fragments, 32768 bf16 (MFMA B-operand order)
#define OFF_MS1T  16384u      // float2[512*1024] (mu,std) at [h][i]
#define OFF_MS2T  1064960u    // float2[256*512]  (mu,std) at [o][h]
#define OFF_B1S   1327104u    // 150*512 = 76800
#define OFF_B2S   1403904u    // 150*256 = 38400
#define OFF_HB    1442304u    // h bf16 FRAGMENT layout [n][s:16][bh:2][qp:4][b16:16][j:8]
                              // element (n, b, h): s=h>>5, qp=(h>>3)&3, j=h&7, bh=b>>4, b16=b&15

// sqrt(2)-folded ErfInv coefficients
#define SQ2 1.41421354f

// Main-branch Horner re-based into z = log2(t) domain:
//   w = -ln2*z ; ww = w-2.5 = -ln2*(z + 2.5/ln2) ; coeffs folded by (-ln2)^k.
#define DSQ2 1.4142135623730951
#define DA  (-0.6931471805599453)
#define ZC3 ((float)(DSQ2 * -4.39150654e-06 * DA*DA*DA*DA*DA))
#define ZC4 ((float)(DSQ2 * 0.00021858087   * DA*DA*DA*DA))
#define ZC5 ((float)(DSQ2 * -0.00125372503  * DA*DA*DA))
#define ZC6 ((float)(DSQ2 * -0.00417768164  * DA*DA))
#define ZC7 ((float)(DSQ2 * 0.246640727     * DA))
#define ZC8 ((float)(DSQ2 * 1.50140941))
#define ZSHIFT 3.6067376022224085f   /* 2.5/ln2 */
#define ZCUT  -7.213475204444817f    /* -(5/ln2): main branch iff z > ZCUT */

// Tail coeffs (exact, sqrt(2)-folded)
#define TT0 (SQ2 * -0.000200214257f)
#define TT1 (SQ2 * 0.000100950558f)
#define TT2 (SQ2 * 0.00134934322f)
#define TT3 (SQ2 * -0.00367342844f)
#define TT4 (SQ2 * 0.00573950773f)
#define TT5 (SQ2 * -0.0076224613f)
#define TT6 (SQ2 * 0.00943887047f)
#define TT7 (SQ2 * 1.00167406f)
#define TT8 (SQ2 * 2.83297682f)

// ---------- threefry-2x32 (JAX-exact, 20 rounds) ----------
#define ROTL32(x, r) __builtin_rotateleft32((x), (r))

__host__ __device__ __forceinline__ void threefry2x32(uint32_t k0, uint32_t k1,
                                                      uint32_t x0, uint32_t x1,
                                                      uint32_t& o0, uint32_t& o1) {
  uint32_t k2 = k0 ^ k1 ^ 0x1BD11BDAu;
  x0 += k0; x1 += k1;
#define TFR(r) { x0 += x1; x1 = ROTL32(x1, r); x1 ^= x0; }
  TFR(13) TFR(15) TFR(26) TFR(6)
  x0 += k1; x1 += k2 + 1u;
  TFR(17) TFR(29) TFR(16) TFR(24)
  x0 += k2; x1 += k0 + 2u;
  TFR(13) TFR(15) TFR(26) TFR(6)
  x0 += k0; x1 += k1 + 3u;
  TFR(17) TFR(29) TFR(16) TFR(24)
  x0 += k1; x1 += k2 + 4u;
  TFR(13) TFR(15) TFR(26) TFR(6)
  x0 += k2; x1 += k0 + 5u;
#undef TFR
  o0 = x0; o1 = x1;
}

// scalar path (bias staging) — exact 9-term
__device__ __forceinline__ float tf_normal(uint32_t k0, uint32_t k1, uint32_t idx) {
  uint32_t o0, o1;
  threefry2x32(k0, k1, 0u, idx, o0, o1);
  uint32_t bits = o0 ^ o1;
  uint32_t fb = (bits >> 9) | 0x3F800000u;
  float m = __uint_as_float(fb);
  const float lo = -0.99999994f;
  float u = fmaxf(fmaf(m, 2.0f, -3.0f), lo);
  float t = fmaf(u, -u, 1.0f);
  float w = -0.69314718056f * __builtin_amdgcn_logf(t);
  float p;
  if (w < 5.0f) {
    float ww = w - 2.5f;
    p = SQ2 * 2.81022636e-08f;
    p = fmaf(p, ww, SQ2 * 3.43273939e-07f);
    p = fmaf(p, ww, SQ2 * -3.5233877e-06f);
    p = fmaf(p, ww, SQ2 * -4.39150654e-06f);
    p = fmaf(p, ww, SQ2 * 0.00021858087f);
    p = fmaf(p, ww, SQ2 * -0.00125372503f);
    p = fmaf(p, ww, SQ2 * -0.00417768164f);
    p = fmaf(p, ww, SQ2 * 0.246640727f);
    p = fmaf(p, ww, SQ2 * 1.50140941f);
  } else {
    float ww = __builtin_amdgcn_sqrtf(w) - 3.0f;
    p = TT0;
    p = fmaf(p, ww, TT1); p = fmaf(p, ww, TT2); p = fmaf(p, ww, TT3);
    p = fmaf(p, ww, TT4); p = fmaf(p, ww, TT5); p = fmaf(p, ww, TT6);
    p = fmaf(p, ww, TT7); p = fmaf(p, ww, TT8);
  }
  return p * u;
}

// ---------- 8-chain threefry: INLINE ASM with injection folding (R2-proven) ----------
#define TF_ADD8 \
  "v_add_u32 %[a0], %[a0], %[b0]\n\t" "v_add_u32 %[a1], %[a1], %[b1]\n\t" \
  "v_add_u32 %[a2], %[a2], %[b2]\n\t" "v_add_u32 %[a3], %[a3], %[b3]\n\t" \
  "v_add_u32 %[a4], %[a4], %[b4]\n\t" "v_add_u32 %[a5], %[a5], %[b5]\n\t" \
  "v_add_u32 %[a6], %[a6], %[b6]\n\t" "v_add_u32 %[a7], %[a7], %[b7]\n\t"
#define TF_ROT8(sh) \
  "v_alignbit_b32 %[b0], %[b0], %[b0], " sh "\n\t" \
  "v_alignbit_b32 %[b1], %[b1], %[b1], " sh "\n\t" \
  "v_alignbit_b32 %[b2], %[b2], %[b2], " sh "\n\t" \
  "v_alignbit_b32 %[b3], %[b3], %[b3], " sh "\n\t" \
  "v_alignbit_b32 %[b4], %[b4], %[b4], " sh "\n\t" \
  "v_alignbit_b32 %[b5], %[b5], %[b5], " sh "\n\t" \
  "v_alignbit_b32 %[b6], %[b6], %[b6], " sh "\n\t" \
  "v_alignbit_b32 %[b7], %[b7], %[b7], " sh "\n\t"
#define TF_XOR8 \
  "v_xor_b32 %[b0], %[b0], %[a0]\n\t" "v_xor_b32 %[b1], %[b1], %[a1]\n\t" \
  "v_xor_b32 %[b2], %[b2], %[a2]\n\t" "v_xor_b32 %[b3], %[b3], %[a3]\n\t" \
  "v_xor_b32 %[b4], %[b4], %[a4]\n\t" "v_xor_b32 %[b5], %[b5], %[a5]\n\t" \
  "v_xor_b32 %[b6], %[b6], %[a6]\n\t" "v_xor_b32 %[b7], %[b7], %[a7]\n\t"
#define TF_ROUND(sh) TF_ADD8 TF_ROT8(sh) TF_XOR8
// round 1: a = k0 + b (SGPR src0)
#define TF_R1(sh) \
  "v_add_u32 %[a0], %[k0], %[b0]\n\t" "v_add_u32 %[a1], %[k0], %[b1]\n\t" \
  "v_add_u32 %[a2], %[k0], %[b2]\n\t" "v_add_u32 %[a3], %[k0], %[b3]\n\t" \
  "v_add_u32 %[a4], %[k0], %[b4]\n\t" "v_add_u32 %[a5], %[k0], %[b5]\n\t" \
  "v_add_u32 %[a6], %[k0], %[b6]\n\t" "v_add_u32 %[a7], %[k0], %[b7]\n\t" \
  TF_ROT8(sh) TF_XOR8
#define TF_BADD8(KB) \
  "v_add_u32 %[b0], " KB ", %[b0]\n\t" "v_add_u32 %[b1], " KB ", %[b1]\n\t" \
  "v_add_u32 %[b2], " KB ", %[b2]\n\t" "v_add_u32 %[b3], " KB ", %[b3]\n\t" \
  "v_add_u32 %[b4], " KB ", %[b4]\n\t" "v_add_u32 %[b5], " KB ", %[b5]\n\t" \
  "v_add_u32 %[b6], " KB ", %[b6]\n\t" "v_add_u32 %[b7], " KB ", %[b7]\n\t"
#define TF_AADD8(KA) \
  "v_add_u32 %[a0], " KA ", %[a0]\n\t" "v_add_u32 %[a1], " KA ", %[a1]\n\t" \
  "v_add_u32 %[a2], " KA ", %[a2]\n\t" "v_add_u32 %[a3], " KA ", %[a3]\n\t" \
  "v_add_u32 %[a4], " KA ", %[a4]\n\t" "v_add_u32 %[a5], " KA ", %[a5]\n\t" \
  "v_add_u32 %[a6], " KA ", %[a6]\n\t" "v_add_u32 %[a7], " KA ", %[a7]\n\t"
#define TF_A3F(KA) \
  "v_add3_u32 %[a0], %[a0], %[b0], " KA "\n\t" \
  "v_add3_u32 %[a1], %[a1], %[b1], " KA "\n\t" \
  "v_add3_u32 %[a2], %[a2], %[b2], " KA "\n\t" \
  "v_add3_u32 %[a3], %[a3], %[b3], " KA "\n\t" \
  "v_add3_u32 %[a4], %[a4], %[b4], " KA "\n\t" \
  "v_add3_u32 %[a5], %[a5], %[b5], " KA "\n\t" \
  "v_add3_u32 %[a6], %[a6], %[b6], " KA "\n\t" \
  "v_add3_u32 %[a7], %[a7], %[b7], " KA "\n\t"
// injection (b += KB) + next round (a = a + b + KA; rot; xor), folded
#define TF_RFOLD(KB, KA, sh) TF_BADD8(KB) TF_A3F(KA) TF_ROT8(sh) TF_XOR8

__device__ __forceinline__ void tf8_bits(uint32_t k0, uint32_t k1, uint32_t k2,
                                         uint32_t idx0, uint32_t* bits) {
  uint32_t k2p1 = k2 + 1u, k0p2 = k0 + 2u, k1p3 = k1 + 3u;
  uint32_t k2p4 = k2 + 4u, k0p5 = k0 + 5u;
  uint32_t t0 = idx0 + k1;
  uint32_t a0, a1, a2, a3, a4, a5, a6, a7;
  uint32_t b0 = t0, b1 = t0 + 1u, b2 = t0 + 2u, b3 = t0 + 3u;
  uint32_t b4 = t0 + 4u, b5 = t0 + 5u, b6 = t0 + 6u, b7 = t0 + 7u;
  asm(TF_R1("19") TF_ROUND("17") TF_ROUND("6") TF_ROUND("26")
      TF_RFOLD("%[k2p1]", "%[k1]", "15")
      TF_ROUND("3") TF_ROUND("16") TF_ROUND("8")
      TF_RFOLD("%[k0p2]", "%[k2]", "19")
      TF_ROUND("17") TF_ROUND("6") TF_ROUND("26")
      TF_RFOLD("%[k1p3]", "%[k0]", "15")
      TF_ROUND("3") TF_ROUND("16") TF_ROUND("8")
      TF_RFOLD("%[k2p4]", "%[k1]", "19")
      TF_ROUND("17") TF_ROUND("6") TF_ROUND("26")
      TF_AADD8("%[k2]") TF_BADD8("%[k0p5]")
      : [a0]"=&v"(a0), [a1]"=&v"(a1), [a2]"=&v"(a2), [a3]"=&v"(a3),
        [a4]"=&v"(a4), [a5]"=&v"(a5), [a6]"=&v"(a6), [a7]"=&v"(a7),
        [b0]"+v"(b0), [b1]"+v"(b1), [b2]"+v"(b2), [b3]"+v"(b3),
        [b4]"+v"(b4), [b5]"+v"(b5), [b6]"+v"(b6), [b7]"+v"(b7)
      : [k0]"s"(k0), [k1]"s"(k1), [k2]"s"(k2), [k2p1]"s"(k2p1),
        [k0p2]"s"(k0p2), [k1p3]"s"(k1p3), [k2p4]"s"(k2p4), [k0p5]"s"(k0p5));
  bits[0] = a0 ^ b0; bits[1] = a1 ^ b1; bits[2] = a2 ^ b2; bits[3] = a3 ^ b3;
  bits[4] = a4 ^ b4; bits[5] = a5 ^ b5; bits[6] = a6 ^ b6; bits[7] = a7 ^ b7;
}

// ---------- transform: scalar C code (R0/R2/R3-proven) ----------
__device__ __forceinline__ float bits_normal(uint32_t bits) {
  uint32_t fb = (bits >> 9) | 0x3F800000u;
  float m = __uint_as_float(fb);
  const float lo = -0.99999994f;
  float u = fmaxf(fmaf(m, 2.0f, -3.0f), lo);
  float t = fmaf(u, -u, 1.0f);
  float z = __builtin_amdgcn_logf(t);          // log2(t) <= 0
  float p;
  if (z > ZCUT) {                              // w < 5 (common)
    float zz = z + ZSHIFT;
    p = ZC3;
    p = fmaf(p, zz, ZC4); p = fmaf(p, zz, ZC5); p = fmaf(p, zz, ZC6);
    p = fmaf(p, zz, ZC7); p = fmaf(p, zz, ZC8);
  } else {                                     // rare tail: exact
    float w = -0.69314718056f * z;
    float ww = __builtin_amdgcn_sqrtf(w) - 3.0f;
    p = TT0;
    p = fmaf(p, ww, TT1); p = fmaf(p, ww, TT2); p = fmaf(p, ww, TT3);
    p = fmaf(p, ww, TT4); p = fmaf(p, ww, TT5); p = fmaf(p, ww, TT6);
    p = fmaf(p, ww, TT7); p = fmaf(p, ww, TT8);
  }
  return p * u;
}

// ---------- prep: full staging (R2-proven) ----------
__global__ __launch_bounds__(256) void prep_kernel(
    const float* __restrict__ x,
    const float* __restrict__ muW1, const float* __restrict__ vW1,
    const float* __restrict__ muW2, const float* __restrict__ vW2,
    const float* __restrict__ mub1, const float* __restrict__ vb1,
    const float* __restrict__ mub2, const float* __restrict__ vb2,
    float* __restrict__ ws,
    uint32_t kb1_0, uint32_t kb1_1, uint32_t kb2_0, uint32_t kb2_1) {
  int bb = blockIdx.x;
  int tid = threadIdx.x;
  if (bb < 2048) {
    int t = bb * 256 + tid;                       // MS1T [h][i] flat
    ((float2*)(ws + OFF_MS1T))[t] = make_float2(muW1[t], expf(vW1[t]));
  } else if (bb < 2560) {
    int t = (bb - 2048) * 256 + tid;              // MS2T [o][h] flat
    ((float2*)(ws + OFF_MS2T))[t] = make_float2(muW2[t], expf(vW2[t]));
  } else if (bb < 2688) {
    int t = (bb - 2560) * 256 + tid;              // x fragments, B-operand order
    int j = t & 7, lane = (t >> 3) & 63, fidx = t >> 9;
    int s = fidx >> 1, f = fidx & 1;
    int b = f * 16 + (lane & 15);
    int k = s * 32 + ((lane >> 4) << 3) + j;
    ((__bf16*)(ws + OFF_XF))[t] = (__bf16)x[b * D_IN + k];
  } else if (bb < 2988) {
    int t = (bb - 2688) * 256 + tid;              // b1s
    int h = t & 511;
    float eps = tf_normal(kb1_0, kb1_1, (uint32_t)t);
    ws[OFF_B1S + t] = fmaf(eps, expf(vb1[h]), mub1[h]);
  } else {
    int t = (bb - 2988) * 256 + tid;              // b2s
    int o = t & 255;
    float eps = tf_normal(kb2_0, kb2_1, (uint32_t)t);
    ws[OFF_B2S + t] = fmaf(eps, expf(vb2[o]), mub2[o]);
  }
}

// ---------- layer 1: K-split 2, 128-thread blocks, staged ms1, fragment store
// (R3-proven 192.2 µs — NO prefetch: R7 proved it costs 14 µs) ----------
__global__ __launch_bounds__(128) void l1_kernel(
    const float* __restrict__ ws, uint32_t k0, uint32_t k1) {
  const float2* __restrict__ ms1 = (const float2*)(ws + OFF_MS1T);
  const bf16x8* __restrict__ xf = (const bf16x8*)(ws + OFF_XF);
  const float* __restrict__ b1s = ws + OFF_B1S;
  __bf16* __restrict__ hB = (__bf16*)(ws + OFF_HB);
  uint32_t k2 = k0 ^ k1 ^ 0x1BD11BDAu;

  __shared__ f32x4 lred[2][64];   // 2048 B

  int lane = threadIdx.x & 63;
  int khalf = threadIdx.x >> 6;
  int tile = blockIdx.x;                 // 0..4799
  int n = tile >> 5;
  int ht = tile & 31;
  int mrow = lane & 15, quad = lane >> 4;
  int h = ht * 16 + mrow;
  uint32_t base = ((uint32_t)(n * 512 + h)) << 10;
  const float2* __restrict__ msrow = ms1 + (size_t)h * D_IN;

  f32x4 acc0 = {0.f, 0.f, 0.f, 0.f}, acc1 = {0.f, 0.f, 0.f, 0.f};

  int send = khalf * 16 + 16;
  for (int s = khalf * 16; s < send; ++s) {
    int kq = s * 32 + quad * 8;
    const f32x4* msq = (const f32x4*)(msrow + kq);
    f32x4 q0 = msq[0], q1 = msq[1], q2 = msq[2], q3 = msq[3];
    bf16x8 b0 = xf[(s * 2 + 0) * 64 + lane];
    bf16x8 b1 = xf[(s * 2 + 1) * 64 + lane];
    uint32_t bits[8];
    tf8_bits(k0, k1, k2, base + (uint32_t)kq, bits);
    float mu[8], sd[8];
    mu[0]=q0[0]; sd[0]=q0[1]; mu[1]=q0[2]; sd[1]=q0[3];
    mu[2]=q1[0]; sd[2]=q1[1]; mu[3]=q1[2]; sd[3]=q1[3];
    mu[4]=q2[0]; sd[4]=q2[1]; mu[5]=q2[2]; sd[5]=q2[3];
    mu[6]=q3[0]; sd[6]=q3[1]; mu[7]=q3[2]; sd[7]=q3[3];
    bf16x8 a;
#pragma unroll
    for (int j = 0; j < 8; ++j) {
      float eps = bits_normal(bits[j]);
      a[j] = (__bf16)fmaf(eps, sd[j], mu[j]);
    }
    acc0 = __builtin_amdgcn_mfma_f32_16x16x32_bf16(a, b0, acc0, 0, 0, 0);
    acc1 = __builtin_amdgcn_mfma_f32_16x16x32_bf16(a, b1, acc1, 0, 0, 0);
  }

  if (khalf) {
    lred[0][lane] = acc0;
    lred[1][lane] = acc1;
  }
  __syncthreads();
  if (!khalf) {
    f32x4 r0 = lred[0][lane], r1 = lred[1][lane];
    acc0 += r0; acc1 += r1;
    int hq = ht * 16 + quad * 4;
    float4 bias = *(const float4*)(b1s + n * 512 + hq);
    float bv[4] = {bias.x, bias.y, bias.z, bias.w};
    union { __bf16 v[4]; uint2 u; } p0, p1;
#pragma unroll
    for (int r = 0; r < 4; ++r) {
      p0.v[r] = (__bf16)fmaxf(acc0[r] + bv[r], 0.0f);
      p1.v[r] = (__bf16)fmaxf(acc1[r] + bv[r], 0.0f);
    }
    // Fragment-layout store: [n][s:16][bh:2][qp:4][b16:16][j:8]  (R3-proven)
    size_t o0 = ((((size_t)(n * 16 + (ht >> 1)) * 2 + 0) * 4 +
                  ((ht & 1) * 2 + (quad >> 1))) * 16 + mrow) * 8 + (quad & 1) * 4;
    *(uint2*)(hB + o0) = p0.u;
    *(uint2*)(hB + o0 + 512) = p1.u;   // bh=1 stride = 4*16*8 = 512 bf16
  }
}

// ---------- layer 2: K-split 2, 256-thread blocks, 2 tiles/block, staged ms2,
// coalesced fragment hB loads (R6-proven best residual — NO prefetch) ----------
__global__ __launch_bounds__(256) void l2_kernel(
    const float* __restrict__ ws, float* __restrict__ y,
    uint32_t k0, uint32_t k1) {
  const float2* __restrict__ ms2 = (const float2*)(ws + OFF_MS2T);
  const bf16x8* __restrict__ hB8 = (const bf16x8*)(ws + OFF_HB);
  const float* __restrict__ b2s = ws + OFF_B2S;
  uint32_t k2 = k0 ^ k1 ^ 0x1BD11BDAu;

  __shared__ f32x4 lred[2][2][64];   // 4096 B

  int lane = threadIdx.x & 63;
  int wib = threadIdx.x >> 6;
  int pairIdx = wib >> 1, khalf = wib & 1;
  int tile = blockIdx.x * 2 + pairIdx;   // 0..2399
  int n = tile >> 4;
  int ot = tile & 15;
  int mrow = lane & 15, quad = lane >> 4;
  int o = ot * 16 + mrow;
  uint32_t base = (uint32_t)(n * 256 + o) << 9;
  const float2* __restrict__ msrow = ms2 + (size_t)o * D_H;

  f32x4 acc0 = {0.f, 0.f, 0.f, 0.f}, acc1 = {0.f, 0.f, 0.f, 0.f};

  int send = khalf * 8 + 8;
  for (int s = khalf * 8; s < send; ++s) {
    int kq = s * 32 + quad * 8;
    const f32x4* msq = (const f32x4*)(msrow + kq);
    f32x4 q0 = msq[0], q1 = msq[1], q2 = msq[2], q3 = msq[3];
    // Fragment-layout load: fully coalesced (lane*16B within a 1KB segment)
    const bf16x8* hf = hB8 + (size_t)((n * 16 + s) * 2) * 64;
    bf16x8 b0 = hf[lane];
    bf16x8 b1 = hf[64 + lane];
    uint32_t bits[8];
    tf8_bits(k0, k1, k2, base + (uint32_t)kq, bits);
    float mu[8], sd[8];
    mu[0]=q0[0]; sd[0]=q0[1]; mu[1]=q0[2]; sd[1]=q0[3];
    mu[2]=q1[0]; sd[2]=q1[1]; mu[3]=q1[2]; sd[3]=q1[3];
    mu[4]=q2[0]; sd[4]=q2[1]; mu[5]=q2[2]; sd[5]=q2[3];
    mu[6]=q3[0]; sd[6]=q3[1]; mu[7]=q3[2]; sd[7]=q3[3];
    bf16x8 a;
#pragma unroll
    for (int j = 0; j < 8; ++j) {
      float eps = bits_normal(bits[j]);
      a[j] = (__bf16)fmaf(eps, sd[j], mu[j]);
    }
    acc0 = __builtin_amdgcn_mfma_f32_16x16x32_bf16(a, b0, acc0, 0, 0, 0);
    acc1 = __builtin_amdgcn_mfma_f32_16x16x32_bf16(a, b1, acc1, 0, 0, 0);
  }

  if (khalf) {
    lred[pairIdx][0][lane] = acc0;
    lred[pairIdx][1][lane] = acc1;
  }
  __syncthreads();
  if (!khalf) {
    f32x4 r0 = lred[pairIdx][0][lane], r1 = lred[pairIdx][1][lane];
    acc0 += r0; acc1 += r1;
    int oq = ot * 16 + quad * 4;
    float4 bias = *(const float4*)(b2s + n * 256 + oq);
    float4 o0, o1;
    o0.x = acc0[0] + bias.x; o0.y = acc0[1] + bias.y;
    o0.z = acc0[2] + bias.z; o0.w = acc0[3] + bias.w;
    o1.x = acc1[0] + bias.x; o1.y = acc1[1] + bias.y;
    o1.z = acc1[2] + bias.z; o1.w = acc1[3] + bias.w;
    *(float4*)(y + (size_t)(n * 32 + mrow) * 256 + oq) = o0;
    *(float4*)(y + (size_t)(n * 32 + 16 + mrow) * 256 + oq) = o1;
  }
}

extern "C" void kernel_launch(void* const* d_in, const int* in_sizes, int n_in,
                              void* d_out, int out_size, void* d_ws, size_t ws_size,
                              hipStream_t stream) {
  const float* x = (const float*)d_in[0];
  const float* muW1 = (const float*)d_in[1];
  const float* mub1 = (const float*)d_in[2];
  const float* muW2 = (const float*)d_in[3];
  const float* mub2 = (const float*)d_in[4];
  const float* vW1 = (const float*)d_in[5];
  const float* vb1 = (const float*)d_in[6];
  const float* vW2 = (const float*)d_in[7];
  const float* vb2 = (const float*)d_in[8];
  float* y = (float*)d_out;
  float* ws = (float*)d_ws;

  uint32_t nk[4][2];
  for (uint32_t j = 0; j < 4; ++j) {
    threefry2x32(0u, 42u, 0u, j, nk[j][0], nk[j][1]);
  }
  // eW1=nk[0], eb1=nk[1], eW2=nk[2], eb2=nk[3]

  prep_kernel<<<3138, 256, 0, stream>>>(
      x, muW1, vW1, muW2, vW2, mub1, vb1, mub2, vb2, ws,
      nk[1][0], nk[1][1], nk[3][0], nk[3][1]);

  // l1: 4800 tiles, one per 128-thread block (2 k-half waves)
  l1_kernel<<<4800, 128, 0, stream>>>(ws, nk[0][0], nk[0][1]);

  // l2: 2400 tiles x 2 k-halves = 4800 waves -> 1200 blocks x 256
  l2_kernel<<<1200, 256, 0, stream>>>(ws, y, nk[2][0], nk[2][1]);
}